// Round 3
// baseline (574.833 us; speedup 1.0000x reference)
//
#include <hip/hip_runtime.h>

// Fusedmax: out = sparsemax(prox_TV1D(x, alpha=1)) row-wise. B=4096, N=512, fp32.
// R3: Johnson DP (glmgen tf_dp), fully LDS-resident (R2's d_ws OOB spill removed).
// One wave per row; lane 0 runs the serial DP:
//   - ys[512]: y stream; tm[i] overlays slot i (dead after iter i-1 prefetch);
//     betas overlay ys in the backward pass; sparsemax reads betas from ys.
//   - kxb[1024]: knot (x,b) packed as float2 -> pop = one ds_read_b64.
//     ka[1024]: knot a as short. tpk[512]: tp.
//   - deque tops cached in REGISTERS: common path (no pops) has zero LDS deps.
//     Rare l==r collisions re-sync regs to mirror glmgen's LDS state exactly.
// LDS = 2 + 8 + 2 + 2 KB = 14336 B -> 11 blocks/CU. No d_ws use; d_out written
// once at the end (deterministic under harness poisoning).

#define TVN 512
#define LAM 1.0f

__device__ __forceinline__ float wave_reduce_sum(float v) {
#pragma unroll
    for (int off = 32; off > 0; off >>= 1) v += __shfl_xor(v, off, 64);
    return v;
}

__global__ __launch_bounds__(64, 4) void fusedmax_kernel(const float* __restrict__ xin,
                                                         float* __restrict__ out) {
    __shared__ __align__(16) float ys[TVN];        // y -> tm overlay -> beta overlay
    __shared__ __align__(16) float2 kxb[2 * TVN];  // knot (x, b)
    __shared__ short ka[2 * TVN];                  // knot a
    __shared__ __align__(16) float tpk[TVN];       // tp

    const int t = threadIdx.x;
    const int row = blockIdx.x;

    // ---- stage row into LDS, coalesced ----
    const float4* __restrict__ g4 = (const float4*)(xin + (size_t)row * TVN);
    float4* s4 = (float4*)ys;
    s4[t] = g4[t];
    s4[t + 64] = g4[t + 64];
    __syncthreads();

    if (t == 0) {
        // ---------- forward pass (Johnson/glmgen tf_dp) ----------
        float y0 = ys[0];
        float ycur = ys[1];
        int l = TVN - 1, r = TVN;
        // initial knots: registers + write-through
        float xlt = y0 - LAM, alt = 1.0f, blt = LAM - y0;
        float xrt = y0 + LAM, art = -1.0f, brt = LAM + y0;
        kxb[l] = make_float2(xlt, blt); ka[l] = 1;
        kxb[r] = make_float2(xrt, brt); ka[r] = -1;
        ys[0] = xlt;       // tm[0] overlay (y[0] already consumed)
        tpk[0] = xrt;
        float ynext = ys[2];

#pragma unroll 1
        for (int i = 1; i < TVN - 1; ++i) {
            float bfirst = -LAM - ycur;
            float blast = -LAM + ycur;
            // ---- left scan (probe register top first) ----
            float alo = 1.0f, blo = bfirst;
            int lo = l;
            {
                float xv = xlt, av = alt, bv = blt;
                if (fmaf(alo, xv, blo) <= -LAM) {
                    do {
                        alo += av; blo += bv;
                        ++lo;
                        if (lo > r) break;
                        float2 kn = kxb[lo];
                        av = (float)ka[lo];
                        xv = kn.x; bv = kn.y;
                    } while (fmaf(alo, xv, blo) <= -LAM);
                }
            }
            float tmv = -LAM - blo;
            if (alo != 1.0f) tmv /= alo;
            l = lo - 1;
            xlt = tmv; alt = alo; blt = blo + LAM;
            kxb[l] = make_float2(xlt, blt); ka[l] = (short)alo;
            if (l == r) { xrt = xlt; art = alt; brt = blt; }   // rare: left ate whole deque

            // ---- right scan ----
            float ahi = -1.0f, bhi = blast;
            int hi = r;
            {
                float xv = xrt, av = art, bv = brt;
                if (-fmaf(ahi, xv, bhi) >= LAM) {
                    do {
                        ahi += av; bhi += bv;
                        --hi;
                        if (hi < l) break;
                        float2 kn = kxb[hi];
                        av = (float)ka[hi];
                        xv = kn.x; bv = kn.y;
                    } while (-fmaf(ahi, xv, bhi) >= LAM);
                }
            }
            float tpv = LAM + bhi;
            if (ahi != -1.0f) tpv /= -ahi;
            r = hi + 1;
            xrt = tpv; art = ahi; brt = bhi + LAM;
            kxb[r] = make_float2(xrt, brt); ka[r] = (short)ahi;
            if (r == l) { xlt = xrt; alt = art; blt = brt; }   // rare: right ate whole deque

            ys[i] = tmv;       // tm overlay
            tpk[i] = tpv;
            ycur = ynext;
            ynext = ys[(i + 2 < TVN) ? (i + 2) : (TVN - 1)];   // prefetch (slot > i: not overlaid yet)
        }

        // ---- last coefficient: minimize (derivative == 0) ----
        float alo = 1.0f, blo = -LAM - ycur;   // ycur == y[N-1]
        {
            int lo = l;
            float xv = xlt, av = alt, bv = blt;
            if (fmaf(alo, xv, blo) <= 0.0f) {
                do {
                    alo += av; blo += bv;
                    ++lo;
                    if (lo > r) break;
                    float2 kn = kxb[lo];
                    av = (float)ka[lo];
                    xv = kn.x; bv = kn.y;
                } while (fmaf(alo, xv, blo) <= 0.0f);
            }
        }
        float b_prev = -blo / alo;

        // ---------- backward: beta[i] = clip(beta[i+1], tm[i], tp[i]), overlay ys ----------
        ys[TVN - 1] = b_prev;
        for (int i = TVN - 2; i >= TVN - 4; --i) {   // scalar head: 510,509,508
            b_prev = fminf(fmaxf(b_prev, ys[i]), tpk[i]);
            ys[i] = b_prev;
        }
        float4* __restrict__ ym4 = (float4*)ys;
        const float4* __restrict__ tp4 = (const float4*)tpk;
#pragma unroll 4
        for (int g = 126; g >= 0; --g) {             // indices 507..0
            float4 tm_ = ym4[g];
            float4 tp_ = tp4[g];
            float4 bo;
            b_prev = fminf(fmaxf(b_prev, tm_.w), tp_.w); bo.w = b_prev;
            b_prev = fminf(fmaxf(b_prev, tm_.z), tp_.z); bo.z = b_prev;
            b_prev = fminf(fmaxf(b_prev, tm_.y), tp_.y); bo.y = b_prev;
            b_prev = fminf(fmaxf(b_prev, tm_.x), tp_.x); bo.x = b_prev;
            ym4[g] = bo;
        }
    }
    __syncthreads();

    // ---------- sparsemax via Michelot fixed point over betas in ys ----------
    float4 a = ((const float4*)ys)[t];
    float4 b = ((const float4*)ys)[t + 64];
    float v[8] = {a.x, a.y, a.z, a.w, b.x, b.y, b.z, b.w};

    float ls = v[0] + v[1] + v[2] + v[3] + v[4] + v[5] + v[6] + v[7];
    float S = wave_reduce_sum(ls);
    float tau = (S - 1.0f) * (1.0f / (float)TVN);
    int cprev = TVN;
#pragma unroll 1
    for (int it = 0; it < TVN; ++it) {
        float s = 0.0f, c = 0.0f;
#pragma unroll
        for (int j = 0; j < 8; ++j) {
            if (v[j] > tau) { s += v[j]; c += 1.0f; }
        }
        s = wave_reduce_sum(s);
        c = wave_reduce_sum(c);
        tau = (s - 1.0f) / c;
        int ci = (int)c;
        if (ci == cprev) break;
        cprev = ci;
    }

    float4 oa, ob;
    oa.x = fmaxf(v[0] - tau, 0.0f);
    oa.y = fmaxf(v[1] - tau, 0.0f);
    oa.z = fmaxf(v[2] - tau, 0.0f);
    oa.w = fmaxf(v[3] - tau, 0.0f);
    ob.x = fmaxf(v[4] - tau, 0.0f);
    ob.y = fmaxf(v[5] - tau, 0.0f);
    ob.z = fmaxf(v[6] - tau, 0.0f);
    ob.w = fmaxf(v[7] - tau, 0.0f);
    float4* __restrict__ o4 = (float4*)(out + (size_t)row * TVN);
    o4[t] = oa;
    o4[t + 64] = ob;
}

extern "C" void kernel_launch(void* const* d_in, const int* in_sizes, int n_in,
                              void* d_out, int out_size, void* d_ws, size_t ws_size,
                              hipStream_t stream) {
    const float* x = (const float*)d_in[0];
    float* out = (float*)d_out;
    const int rows = in_sizes[0] / TVN;   // 4096
    fusedmax_kernel<<<dim3(rows), dim3(64), 0, stream>>>(x, out);
}